// Round 7
// baseline (168.268 us; speedup 1.0000x reference)
//
#include <hip/hip_runtime.h>
#include <math.h>

#define NB 32
#define NP 8732
#define NC 81
#define NM 20
#define CHUNKS 35                 // ceil(NP/256)
#define NROWS (NB * NP)           // 279424
#define NGROUPS (NROWS / 4)       // 69856 groups of 4 rows
#define CE_BLOCKS (NGROUPS / 4)   // 17464 blocks, 4 waves each, 1 group/wave

typedef unsigned long long ull;
#define AGENT __HIP_MEMORY_SCOPE_AGENT

// ws byte layout (first 4096 B zeroed by memset node each replay):
//  [0)    acc float[3]: 0=loc_sum 1=conf_pos 2=conf_neg ; [12) minedone int
//  [64)   nposarr int[NB]
//  [192)  chunkdone int[NB]
//  [320)  perimgPos float[NB]
//  [448)  perimgLoc float[NB]
//  [4096) bestpart ull[NB*CHUNKS*NM]   (179200 B)
//  [196608)  labobj u32[NROWS]         (1117696 B)  lab | obj<<8
//  [1314304) neg f32[NROWS]            (1117696 B)

// ---------------- K1: match + force-assign (fused) ----------------
__global__ __launch_bounds__(256)
void match_force_kernel(const float* __restrict__ boxes,
                        const int*   __restrict__ labels,
                        const float* __restrict__ priors,
                        ull*      __restrict__ bestpart,
                        unsigned* __restrict__ labobj,
                        int*      __restrict__ chunkdone)
{
    const int b = blockIdx.x / CHUNKS;
    const int chunk = blockIdx.x % CHUNKS;
    const int tid = threadIdx.x;
    const int p = chunk * 256 + tid;
    const bool valid = p < NP;

    __shared__ float bxs[NM][4];
    __shared__ float areaA[NM];
    __shared__ int   labL[NM];
    __shared__ float iouT[256 * 21];   // stride 21: conflict-free transpose
    __shared__ ull   wcand[4][NM];
    __shared__ int   flagLast;
    __shared__ int   pps[NM];

    if (tid < NM * 4) ((float*)bxs)[tid] = boxes[b * NM * 4 + tid];
    if (tid >= 128 && tid < 128 + NM) labL[tid - 128] = labels[b * NM + (tid - 128)];
    if (tid == 0) flagLast = 0;
    __syncthreads();
    if (tid < NM) areaA[tid] = (bxs[tid][2] - bxs[tid][0]) * (bxs[tid][3] - bxs[tid][1]);
    __syncthreads();

    float4 pc = reinterpret_cast<const float4*>(priors)[valid ? p : 0];
    const float px1 = pc.x - pc.z * 0.5f;
    const float py1 = pc.y - pc.w * 0.5f;
    const float px2 = pc.x + pc.z * 0.5f;
    const float py2 = pc.y + pc.w * 0.5f;
    const float pa  = (px2 - px1) * (py2 - py1);

    float bov = -1.f; int bm = 0;
    const int tbase = tid * 21;
#pragma unroll
    for (int m = 0; m < NM; m++) {
        float ix1 = fmaxf(bxs[m][0], px1);
        float iy1 = fmaxf(bxs[m][1], py1);
        float ix2 = fminf(bxs[m][2], px2);
        float iy2 = fminf(bxs[m][3], py2);
        float iw = fmaxf(ix2 - ix1, 0.f);
        float ih = fmaxf(iy2 - iy1, 0.f);
        float inter = iw * ih;
        float iou = inter / (areaA[m] + pa - inter);
        if (iou > bov) { bov = iou; bm = m; }          // first-max over m
        iouT[tbase + m] = valid ? iou : -1.f;
    }
    if (valid) {
        int lab = (bov < 0.5f) ? 0 : labL[bm];
        __hip_atomic_store(&labobj[(size_t)b * NP + p],
                           (unsigned)lab | ((unsigned)bm << 8),
                           __ATOMIC_RELAXED, AGENT);
    }
    __syncthreads();

    // per-object argmax over this chunk's 256 priors: wave w scans its 64 rows
    const int lane = tid & 63, wid = tid >> 6;
    if (lane < NM) {
        const int m = lane;
        float bv = -1.f; int bt = 0;
        const int t0 = wid * 64;
        for (int t = t0; t < t0 + 64; t++) {
            float v = iouT[t * 21 + m];
            if (v > bv) { bv = v; bt = t; }            // strict > keeps min index
        }
        wcand[wid][m] = (bv < 0.f) ? 0ull
            : ((((ull)__float_as_uint(bv)) << 32) | (unsigned)~(unsigned)(chunk * 256 + bt));
    }
    __syncthreads();
    if (tid < NM) {
        ull k = wcand[0][tid];
        if (wcand[1][tid] > k) k = wcand[1][tid];
        if (wcand[2][tid] > k) k = wcand[2][tid];
        if (wcand[3][tid] > k) k = wcand[3][tid];
        __hip_atomic_store(&bestpart[(size_t)(b * CHUNKS + chunk) * NM + tid], k,
                           __ATOMIC_RELAXED, AGENT);
    }
    __syncthreads();
    if (tid == 0) {
        int old = __hip_atomic_fetch_add(&chunkdone[b], 1, __ATOMIC_ACQ_REL, AGENT);
        if (old == CHUNKS - 1) flagLast = 1;
    }
    __syncthreads();

    if (flagLast) {                                    // force-assign (one block/image)
        if (tid < NM) {
            ull k = 0ull;
            for (int c = 0; c < CHUNKS; c++) {
                ull v = __hip_atomic_load(&bestpart[(size_t)(b * CHUNKS + c) * NM + tid],
                                          __ATOMIC_RELAXED, AGENT);
                if (v > k) k = v;
            }
            pps[tid] = (int)~(unsigned)(k & 0xFFFFFFFFull);
        }
        __syncthreads();
        if (tid < NM) {
            int pp = pps[tid];
            bool win = true;
            for (int m2 = tid + 1; m2 < NM; m2++)
                if (pps[m2] == pp) win = false;        // last-write-wins
            if (win)
                __hip_atomic_store(&labobj[(size_t)b * NP + pp],
                                   (unsigned)labL[tid] | ((unsigned)tid << 8),
                                   __ATOMIC_RELAXED, AGENT);
        }
    }
}

// ---------------- K2: coalesced CE, one wave per 4 rows ----------------
#define ACCEL(val, e) { float ex_ = __expf(val); \
    s0 += (e) < 81 ? ex_ : 0.f; \
    s1 += ((e) >= 81 && (e) < 162) ? ex_ : 0.f; \
    s2 += ((e) >= 162 && (e) < 243) ? ex_ : 0.f; \
    s3 += (e) >= 243 ? ex_ : 0.f; }

__global__ __launch_bounds__(256)
void ce_kernel(const float* __restrict__ scores,
               const float* __restrict__ plocs,
               const float* __restrict__ boxes,
               const float* __restrict__ priors,
               const unsigned* __restrict__ labobj,
               float* __restrict__ neg,
               float* __restrict__ perimgPos,
               float* __restrict__ perimgLoc,
               int*   __restrict__ nposarr)
{
    __shared__ float bsum, blocsum;
    __shared__ int   bnp[2];
    const int tid = threadIdx.x;
    const int lane = tid & 63;
    if (tid == 0) { bsum = 0.f; blocsum = 0.f; }
    if (tid < 2) bnp[tid] = 0;
    __syncthreads();

    // group of 4 rows = 324 floats = exactly 81 float4, 16B-aligned
    const long long g = (long long)blockIdx.x * 4 + (tid >> 6);
    const float4* gsrc = reinterpret_cast<const float4*>(scores) + (size_t)g * 81;

    float s0 = 0.f, s1 = 0.f, s2 = 0.f, s3 = 0.f;
    float4 A = gsrc[lane];                       // elements 4*lane .. 4*lane+3
    if (lane < 17) {                             // elements 256.. 323: all row 3
        float4 B4 = gsrc[64 + lane];
        s3 = (__expf(B4.x) + __expf(B4.y)) + (__expf(B4.z) + __expf(B4.w));
    }
    const int e0 = lane * 4;
    ACCEL(A.x, e0)
    ACCEL(A.y, e0 + 1)
    ACCEL(A.z, e0 + 2)
    ACCEL(A.w, e0 + 3)

#pragma unroll
    for (int off = 1; off < 64; off <<= 1) {
        s0 += __shfl_xor(s0, off);
        s1 += __shfl_xor(s1, off);
        s2 += __shfl_xor(s2, off);
        s3 += __shfl_xor(s3, off);
    }

    if (lane < 4) {
        float srow = (lane == 0) ? s0 : (lane == 1) ? s1 : (lane == 2) ? s2 : s3;
        const long long r = g * 4 + lane;
        const int b = (int)(r / NP);
        const int p = (int)(r - (long long)b * NP);
        const int bfirst = (int)(((long long)blockIdx.x * 16) / NP);
        const unsigned lo = labobj[r];
        const int lab = lo & 0xFF;
        const int obj = lo >> 8;
        float labval = scores[(size_t)r * NC + lab];   // L1-hit: line just fetched
        float ce = logf(srow) - labval;                // no-max LSE: |x|<~6, no overflow

        if (lab > 0) {
            neg[r] = 0.f;
            atomicAdd(&bsum, ce);
            atomicAdd(&bnp[b - bfirst], 1);
            float4 pcr = reinterpret_cast<const float4*>(priors)[p];
            const float* bx = boxes + ((size_t)b * NM + obj) * 4;
            float x1 = bx[0], y1 = bx[1], x2 = bx[2], y2 = bx[3];
            float bcx = (x1 + x2) * 0.5f, bcy = (y1 + y2) * 0.5f;
            float bw = x2 - x1, bh = y2 - y1;
            float g0 = (bcx - pcr.x) / (pcr.z / 10.f);
            float g1 = (bcy - pcr.y) / (pcr.w / 10.f);
            float g2 = logf(bw / pcr.z) * 5.f;
            float g3 = logf(bh / pcr.w) * 5.f;
            float4 pl = reinterpret_cast<const float4*>(plocs)[r];
            float t = 0.f, d, ad;
            d = pl.x - g0; ad = fabsf(d); t += (ad < 1.f) ? 0.5f * d * d : ad - 0.5f;
            d = pl.y - g1; ad = fabsf(d); t += (ad < 1.f) ? 0.5f * d * d : ad - 0.5f;
            d = pl.z - g2; ad = fabsf(d); t += (ad < 1.f) ? 0.5f * d * d : ad - 0.5f;
            d = pl.w - g3; ad = fabsf(d); t += (ad < 1.f) ? 0.5f * d * d : ad - 0.5f;
            atomicAdd(&blocsum, t);
        } else {
            neg[r] = ce;
        }
    }
    __syncthreads();
    if (tid == 0) {
        const int bfirst = (int)(((long long)blockIdx.x * 16) / NP);
        if (bsum != 0.f)    atomicAdd(&perimgPos[bfirst], bsum);
        if (blocsum != 0.f) atomicAdd(&perimgLoc[bfirst], blocsum);
        if (bnp[0] > 0)     atomicAdd(&nposarr[bfirst], bnp[0]);
        if (bnp[1] > 0)     atomicAdd(&nposarr[bfirst + 1], bnp[1]);
    }
}

// ---------------- K3: hard-negative mining + fold + finalize ----------------
__global__ __launch_bounds__(1024)
void mine_kernel(const float* __restrict__ neg,
                 const int*   __restrict__ nposarr,
                 const float* __restrict__ perimgPos,
                 const float* __restrict__ perimgLoc,
                 float* __restrict__ acc,
                 float* __restrict__ out)
{
    __shared__ float vals[NP];
    __shared__ ull   redU[2][16];
    __shared__ float redF[16];
    __shared__ int   redI[16];
    const int b = blockIdx.x;
    const int tid = threadIdx.x;
    const float* src = neg + (size_t)b * NP;
    for (int p = tid; p < NP; p += 1024) vals[p] = src[p];
    int k = nposarr[b] * 3;
    if (k > NP) k = NP;
    __syncthreads();
    const int lane = tid & 63, wid = tid >> 6;

    float t = 0.f;
    if (k > 0) {
        unsigned lo = 0u, hi = 0x7f7fffffu;
        int par = 0;
        while (lo < hi) {
            unsigned u1, u2, u3;
            if (hi - lo >= 3u) {
                unsigned w4 = (hi - lo + 1u) >> 2;
                u1 = lo + w4; u2 = lo + 2u * w4; u3 = lo + 3u * w4;
            } else {
                u1 = u2 = u3 = lo + ((hi - lo + 1u) >> 1);
            }
            float t1 = __uint_as_float(u1), t2 = __uint_as_float(u2), t3 = __uint_as_float(u3);
            ull c = 0ull;
            for (int p = tid; p < NP; p += 1024) {
                float v = vals[p];
                c += (v >= t1 ? 1ull : 0ull)
                   + (v >= t2 ? (1ull << 21) : 0ull)
                   + (v >= t3 ? (1ull << 42) : 0ull);
            }
#pragma unroll
            for (int off = 32; off; off >>= 1) c += __shfl_xor(c, off);
            if (lane == 0) redU[par][wid] = c;
            __syncthreads();
            ull tot = 0ull;
#pragma unroll
            for (int w = 0; w < 16; w++) tot += redU[par][w];
            par ^= 1;                       // next iter writes other buffer: 1 barrier/iter
            int c1 = (int)(tot & 0x1FFFFFull);
            int c2 = (int)((tot >> 21) & 0x1FFFFFull);
            int c3 = (int)(tot >> 42);
            if      (c3 >= k) lo = u3;
            else if (c2 >= k) { lo = u2; hi = u3 - 1u; }
            else if (c1 >= k) { lo = u1; hi = u2 - 1u; }
            else              hi = u1 - 1u;
        }
        t = __uint_as_float(lo);            // exact k-th largest
    }
    float s = 0.f; int cg = 0;
    for (int p = tid; p < NP; p += 1024) {
        float v = vals[p];
        if (v > t) { s += v; cg++; }
    }
#pragma unroll
    for (int off = 32; off; off >>= 1) { s += __shfl_down(s, off); cg += __shfl_down(cg, off); }
    if (lane == 0) { redF[wid] = s; redI[wid] = cg; }
    __syncthreads();
    if (tid == 0) {
        float sum = 0.f; int cG = 0;
#pragma unroll
        for (int w = 0; w < 16; w++) { sum += redF[w]; cG += redI[w]; }
        float contrib = (k > 0) ? (sum + (float)(k - cG) * t) : 0.f;
        atomicAdd(&acc[2], contrib);
        atomicAdd(&acc[1], perimgPos[b]);   // fold per-image CE partials (32 adds total)
        atomicAdd(&acc[0], perimgLoc[b]);
        __threadfence();
        int old = atomicAdd((int*)acc + 3, 1);
        if (old == NB - 1) {                // last block: finalize
            __threadfence();
            float nt = 0.f;
            for (int i = 0; i < NB; i++) nt += (float)nposarr[i];
            out[0] = (acc[2] + acc[1]) / nt;   // conf_loss
            out[1] = acc[0] / (nt * 4.f);      // loc_loss (ALPHA=1)
        }
    }
}

extern "C" void kernel_launch(void* const* d_in, const int* in_sizes, int n_in,
                              void* d_out, int out_size, void* d_ws, size_t ws_size,
                              hipStream_t stream)
{
    const float* plocs  = (const float*)d_in[0];
    const float* scores = (const float*)d_in[1];
    const float* boxes  = (const float*)d_in[2];
    const int*   labels = (const int*)d_in[3];
    const float* priors = (const float*)d_in[4];
    float* out = (float*)d_out;

    char* base = (char*)d_ws;
    float*    acc       = (float*)base;
    int*      nposarr   = (int*)(base + 64);
    int*      chunkdone = (int*)(base + 192);
    float*    perimgPos = (float*)(base + 320);
    float*    perimgLoc = (float*)(base + 448);
    ull*      bestpart  = (ull*)(base + 4096);
    unsigned* labobj    = (unsigned*)(base + 196608);
    float*    neg       = (float*)(base + 1314304);

    hipMemsetAsync(d_ws, 0, 4096, stream);
    hipLaunchKernelGGL(match_force_kernel, dim3(NB * CHUNKS), dim3(256), 0, stream,
                       boxes, labels, priors, bestpart, labobj, chunkdone);
    hipLaunchKernelGGL(ce_kernel, dim3(CE_BLOCKS), dim3(256), 0, stream,
                       scores, plocs, boxes, priors, labobj, neg,
                       perimgPos, perimgLoc, nposarr);
    hipLaunchKernelGGL(mine_kernel, dim3(NB), dim3(1024), 0, stream,
                       neg, nposarr, perimgPos, perimgLoc, acc, out);
}

// Round 8
// 120.005 us; speedup vs baseline: 1.4022x; 1.4022x over previous
//
#include <hip/hip_runtime.h>
#include <math.h>

#define NB 32
#define NP 8732
#define NC 81
#define NM 20
#define CHUNKS 35                 // ceil(NP/256)
#define NROWS (NB * NP)           // 279424
#define CE_BLOCKS (NROWS / 64)    // 4366 blocks; 64 rows/block, 4 threads/row

typedef unsigned long long ull;
#define AGENT __HIP_MEMORY_SCOPE_AGENT

// ws byte layout (first 4096 B zeroed by memset node each replay):
//  [0)    acc float[3]: 0=loc_sum 1=conf_pos 2=conf_neg ; [12) minedone int
//  [64)   nposarr int[NB]
//  [192)  chunkdone int[NB]
//  [320)  perimgPos float[NB]
//  [448)  perimgLoc float[NB]
//  [4096) bestpart ull[NB*CHUNKS*NM]   (179200 B)
//  [196608)  labobj u32[NROWS]         (1117696 B)  lab | obj<<8
//  [1314304) neg f32[NROWS]            (1117696 B)

// ---------------- K1: match + force-assign (fused) ----------------
__global__ __launch_bounds__(256)
void match_force_kernel(const float* __restrict__ boxes,
                        const int*   __restrict__ labels,
                        const float* __restrict__ priors,
                        ull*      __restrict__ bestpart,
                        unsigned* __restrict__ labobj,
                        int*      __restrict__ chunkdone)
{
    const int b = blockIdx.x / CHUNKS;
    const int chunk = blockIdx.x % CHUNKS;
    const int tid = threadIdx.x;
    const int p = chunk * 256 + tid;
    const bool valid = p < NP;

    __shared__ float bxs[NM][4];
    __shared__ float areaA[NM];
    __shared__ int   labL[NM];
    __shared__ float iouT[256 * 21];   // stride 21: conflict-free transpose
    __shared__ ull   wcand[4][NM];
    __shared__ int   flagLast;
    __shared__ int   pps[NM];

    if (tid < NM * 4) ((float*)bxs)[tid] = boxes[b * NM * 4 + tid];
    if (tid >= 128 && tid < 128 + NM) labL[tid - 128] = labels[b * NM + (tid - 128)];
    if (tid == 0) flagLast = 0;
    __syncthreads();
    if (tid < NM) areaA[tid] = (bxs[tid][2] - bxs[tid][0]) * (bxs[tid][3] - bxs[tid][1]);
    __syncthreads();

    float4 pc = reinterpret_cast<const float4*>(priors)[valid ? p : 0];
    const float px1 = pc.x - pc.z * 0.5f;
    const float py1 = pc.y - pc.w * 0.5f;
    const float px2 = pc.x + pc.z * 0.5f;
    const float py2 = pc.y + pc.w * 0.5f;
    const float pa  = (px2 - px1) * (py2 - py1);

    float bov = -1.f; int bm = 0;
    const int tbase = tid * 21;
#pragma unroll
    for (int m = 0; m < NM; m++) {
        float ix1 = fmaxf(bxs[m][0], px1);
        float iy1 = fmaxf(bxs[m][1], py1);
        float ix2 = fminf(bxs[m][2], px2);
        float iy2 = fminf(bxs[m][3], py2);
        float iw = fmaxf(ix2 - ix1, 0.f);
        float ih = fmaxf(iy2 - iy1, 0.f);
        float inter = iw * ih;
        float iou = inter / (areaA[m] + pa - inter);
        if (iou > bov) { bov = iou; bm = m; }          // first-max over m
        iouT[tbase + m] = valid ? iou : -1.f;
    }
    if (valid) {
        int lab = (bov < 0.5f) ? 0 : labL[bm];
        __hip_atomic_store(&labobj[(size_t)b * NP + p],
                           (unsigned)lab | ((unsigned)bm << 8),
                           __ATOMIC_RELAXED, AGENT);
    }
    __syncthreads();

    // per-object argmax over this chunk's 256 priors: wave w scans its 64 rows
    const int lane = tid & 63, wid = tid >> 6;
    if (lane < NM) {
        const int m = lane;
        float bv = -1.f; int bt = 0;
        const int t0 = wid * 64;
        for (int t = t0; t < t0 + 64; t++) {
            float v = iouT[t * 21 + m];
            if (v > bv) { bv = v; bt = t; }            // strict > keeps min index
        }
        wcand[wid][m] = (bv < 0.f) ? 0ull
            : ((((ull)__float_as_uint(bv)) << 32) | (unsigned)~(unsigned)(chunk * 256 + bt));
    }
    __syncthreads();
    if (tid < NM) {
        ull k = wcand[0][tid];
        if (wcand[1][tid] > k) k = wcand[1][tid];
        if (wcand[2][tid] > k) k = wcand[2][tid];
        if (wcand[3][tid] > k) k = wcand[3][tid];
        __hip_atomic_store(&bestpart[(size_t)(b * CHUNKS + chunk) * NM + tid], k,
                           __ATOMIC_RELAXED, AGENT);
    }
    __syncthreads();
    if (tid == 0) {
        int old = __hip_atomic_fetch_add(&chunkdone[b], 1, __ATOMIC_ACQ_REL, AGENT);
        if (old == CHUNKS - 1) flagLast = 1;
    }
    __syncthreads();

    if (flagLast) {                                    // force-assign (one block/image)
        if (tid < NM) {
            ull k = 0ull;
            for (int c = 0; c < CHUNKS; c++) {
                ull v = __hip_atomic_load(&bestpart[(size_t)(b * CHUNKS + c) * NM + tid],
                                          __ATOMIC_RELAXED, AGENT);
                if (v > k) k = v;
            }
            pps[tid] = (int)~(unsigned)(k & 0xFFFFFFFFull);
        }
        __syncthreads();
        if (tid < NM) {
            int pp = pps[tid];
            bool win = true;
            for (int m2 = tid + 1; m2 < NM; m2++)
                if (pps[m2] == pp) win = false;        // last-write-wins
            if (win)
                __hip_atomic_store(&labobj[(size_t)b * NP + pp],
                                   (unsigned)labL[tid] | ((unsigned)tid << 8),
                                   __ATOMIC_RELAXED, AGENT);
        }
    }
}

// ---------------- K2: CE + loc loss; quad of threads per row ----------------
__global__ __launch_bounds__(256, 8)
void ce_kernel(const float* __restrict__ scores,
               const float* __restrict__ plocs,
               const float* __restrict__ boxes,
               const float* __restrict__ priors,
               const unsigned* __restrict__ labobj,
               float* __restrict__ neg,
               float* __restrict__ perimgPos,
               float* __restrict__ perimgLoc,
               int*   __restrict__ nposarr)
{
    __shared__ float bsum, blocsum;
    __shared__ int   bnp[2];
    const int tid = threadIdx.x;
    if (tid == 0) { bsum = 0.f; blocsum = 0.f; }
    if (tid < 2) bnp[tid] = 0;
    __syncthreads();

    const int rloc = tid >> 2, q = tid & 3;
    const int r = blockIdx.x * 64 + rloc;         // exact: 4366*64 = NROWS
    const int b = r / NP;
    const int p = r - b * NP;
    const int bfirst = (blockIdx.x * 64) / NP;
    const unsigned lo = labobj[r];                // early independent load

    // each quad-lane: contiguous 20-float segment; q==3 also takes elem 80
    const float* row = scores + (size_t)r * NC;
    const int st = q * 20;
    float v[20];
#pragma unroll
    for (int j = 0; j < 20; j++) v[j] = row[st + j];
    float e0 = 0.f, e1 = 0.f, e2 = 0.f, e3 = 0.f;
#pragma unroll
    for (int j = 0; j < 20; j += 4) {
        e0 += __expf(v[j]);
        e1 += __expf(v[j + 1]);
        e2 += __expf(v[j + 2]);
        e3 += __expf(v[j + 3]);
    }
    float s = (e0 + e1) + (e2 + e3);
    if (q == 3) s += __expf(row[80]);
    s += __shfl_xor(s, 1);                        // quad-local: DPP-cheap
    s += __shfl_xor(s, 2);

    if (q == 0) {
        const int lab = lo & 0xFF;
        const int obj = lo >> 8;
        float labval = row[lab];                  // L1-hit: quad just fetched the row
        float ce = logf(s) - labval;              // no-max LSE: |x|<~6, safe

        if (lab > 0) {
            neg[r] = 0.f;
            atomicAdd(&bsum, ce);
            atomicAdd(&bnp[b - bfirst], 1);
            float4 pcr = reinterpret_cast<const float4*>(priors)[p];
            const float* bx = boxes + ((size_t)b * NM + obj) * 4;
            float x1 = bx[0], y1 = bx[1], x2 = bx[2], y2 = bx[3];
            float bcx = (x1 + x2) * 0.5f, bcy = (y1 + y2) * 0.5f;
            float bw = x2 - x1, bh = y2 - y1;
            float g0 = (bcx - pcr.x) / (pcr.z / 10.f);
            float g1 = (bcy - pcr.y) / (pcr.w / 10.f);
            float g2 = logf(bw / pcr.z) * 5.f;
            float g3 = logf(bh / pcr.w) * 5.f;
            float4 pl = reinterpret_cast<const float4*>(plocs)[r];
            float t = 0.f, d, ad;
            d = pl.x - g0; ad = fabsf(d); t += (ad < 1.f) ? 0.5f * d * d : ad - 0.5f;
            d = pl.y - g1; ad = fabsf(d); t += (ad < 1.f) ? 0.5f * d * d : ad - 0.5f;
            d = pl.z - g2; ad = fabsf(d); t += (ad < 1.f) ? 0.5f * d * d : ad - 0.5f;
            d = pl.w - g3; ad = fabsf(d); t += (ad < 1.f) ? 0.5f * d * d : ad - 0.5f;
            atomicAdd(&blocsum, t);
        } else {
            neg[r] = ce;
        }
    }
    __syncthreads();
    if (tid == 0) {
        if (bsum != 0.f)    atomicAdd(&perimgPos[bfirst], bsum);
        if (blocsum != 0.f) atomicAdd(&perimgLoc[bfirst], blocsum);
        if (bnp[0] > 0)     atomicAdd(&nposarr[bfirst], bnp[0]);
        if (bnp[1] > 0)     atomicAdd(&nposarr[bfirst + 1], bnp[1]);
    }
}

// ---------------- K3: hard-negative mining + fold + finalize ----------------
__global__ __launch_bounds__(1024)
void mine_kernel(const float* __restrict__ neg,
                 const int*   __restrict__ nposarr,
                 const float* __restrict__ perimgPos,
                 const float* __restrict__ perimgLoc,
                 float* __restrict__ acc,
                 float* __restrict__ out)
{
    __shared__ float vals[NP];
    __shared__ ull   redU[2][16];
    __shared__ float redF[16];
    __shared__ int   redI[16];
    const int b = blockIdx.x;
    const int tid = threadIdx.x;
    const float* src = neg + (size_t)b * NP;
    for (int p = tid; p < NP; p += 1024) vals[p] = src[p];
    int k = nposarr[b] * 3;
    if (k > NP) k = NP;
    __syncthreads();
    const int lane = tid & 63, wid = tid >> 6;

    float t = 0.f;
    if (k > 0) {
        unsigned lo = 0u, hi = 0x7f7fffffu;
        int par = 0;
        while (lo < hi) {
            unsigned u1, u2, u3;
            if (hi - lo >= 3u) {
                unsigned w4 = (hi - lo + 1u) >> 2;
                u1 = lo + w4; u2 = lo + 2u * w4; u3 = lo + 3u * w4;
            } else {
                u1 = u2 = u3 = lo + ((hi - lo + 1u) >> 1);
            }
            float t1 = __uint_as_float(u1), t2 = __uint_as_float(u2), t3 = __uint_as_float(u3);
            ull c = 0ull;
            for (int p = tid; p < NP; p += 1024) {
                float v = vals[p];
                c += (v >= t1 ? 1ull : 0ull)
                   + (v >= t2 ? (1ull << 21) : 0ull)
                   + (v >= t3 ? (1ull << 42) : 0ull);
            }
#pragma unroll
            for (int off = 32; off; off >>= 1) c += __shfl_xor(c, off);
            if (lane == 0) redU[par][wid] = c;
            __syncthreads();
            ull tot = 0ull;
#pragma unroll
            for (int w = 0; w < 16; w++) tot += redU[par][w];
            par ^= 1;                       // double-buffered: 1 barrier/iter
            int c1 = (int)(tot & 0x1FFFFFull);
            int c2 = (int)((tot >> 21) & 0x1FFFFFull);
            int c3 = (int)(tot >> 42);
            if      (c3 >= k) lo = u3;
            else if (c2 >= k) { lo = u2; hi = u3 - 1u; }
            else if (c1 >= k) { lo = u1; hi = u2 - 1u; }
            else              hi = u1 - 1u;
        }
        t = __uint_as_float(lo);            // exact k-th largest
    }
    float s = 0.f; int cg = 0;
    for (int p = tid; p < NP; p += 1024) {
        float v = vals[p];
        if (v > t) { s += v; cg++; }
    }
#pragma unroll
    for (int off = 32; off; off >>= 1) { s += __shfl_down(s, off); cg += __shfl_down(cg, off); }
    if (lane == 0) { redF[wid] = s; redI[wid] = cg; }
    __syncthreads();
    if (tid == 0) {
        float sum = 0.f; int cG = 0;
#pragma unroll
        for (int w = 0; w < 16; w++) { sum += redF[w]; cG += redI[w]; }
        float contrib = (k > 0) ? (sum + (float)(k - cG) * t) : 0.f;
        atomicAdd(&acc[2], contrib);
        atomicAdd(&acc[1], perimgPos[b]);
        atomicAdd(&acc[0], perimgLoc[b]);
        __threadfence();
        int old = atomicAdd((int*)acc + 3, 1);
        if (old == NB - 1) {                // last block: finalize
            __threadfence();
            float nt = 0.f;
            for (int i = 0; i < NB; i++) nt += (float)nposarr[i];
            out[0] = (acc[2] + acc[1]) / nt;   // conf_loss
            out[1] = acc[0] / (nt * 4.f);      // loc_loss (ALPHA=1)
        }
    }
}

extern "C" void kernel_launch(void* const* d_in, const int* in_sizes, int n_in,
                              void* d_out, int out_size, void* d_ws, size_t ws_size,
                              hipStream_t stream)
{
    const float* plocs  = (const float*)d_in[0];
    const float* scores = (const float*)d_in[1];
    const float* boxes  = (const float*)d_in[2];
    const int*   labels = (const int*)d_in[3];
    const float* priors = (const float*)d_in[4];
    float* out = (float*)d_out;

    char* base = (char*)d_ws;
    float*    acc       = (float*)base;
    int*      nposarr   = (int*)(base + 64);
    int*      chunkdone = (int*)(base + 192);
    float*    perimgPos = (float*)(base + 320);
    float*    perimgLoc = (float*)(base + 448);
    ull*      bestpart  = (ull*)(base + 4096);
    unsigned* labobj    = (unsigned*)(base + 196608);
    float*    neg       = (float*)(base + 1314304);

    hipMemsetAsync(d_ws, 0, 4096, stream);
    hipLaunchKernelGGL(match_force_kernel, dim3(NB * CHUNKS), dim3(256), 0, stream,
                       boxes, labels, priors, bestpart, labobj, chunkdone);
    hipLaunchKernelGGL(ce_kernel, dim3(CE_BLOCKS), dim3(256), 0, stream,
                       scores, plocs, boxes, priors, labobj, neg,
                       perimgPos, perimgLoc, nposarr);
    hipLaunchKernelGGL(mine_kernel, dim3(NB), dim3(1024), 0, stream,
                       neg, nposarr, perimgPos, perimgLoc, acc, out);
}

// Round 9
// 89.723 us; speedup vs baseline: 1.8754x; 1.3375x over previous
//
#include <hip/hip_runtime.h>
#include <math.h>

#define NB 32
#define NP 8732
#define NC 81
#define NM 20
#define CHUNKS 35                 // ceil(NP/256)
#define NROWS (NB * NP)           // 279424
#define NGROUPS (NROWS / 4)       // 69856 groups of 4 rows
#define CE_BLOCKS ((NGROUPS + 63) / 64)   // 1092 blocks; 64 groups (256 rows) per block

typedef unsigned long long ull;
#define AGENT __HIP_MEMORY_SCOPE_AGENT

// ws byte layout (first 4096 B zeroed by memset node each replay):
//  [0)    acc float[3]: 0=loc_sum 1=conf_pos 2=conf_neg ; [12) minedone int
//  [64)   nposarr int[NB]
//  [192)  chunkdone int[NB]
//  [320)  perimgPos float[NB]
//  [448)  perimgLoc float[NB]
//  [4096) bestpart ull[NB*CHUNKS*NM]   (179200 B)
//  [196608)  labobj u32[NROWS]         (1117696 B)  lab | obj<<8
//  [1314304) neg f32[NROWS]            (1117696 B)

// ---------------- K1: match + force-assign (fused) ----------------
__global__ __launch_bounds__(256)
void match_force_kernel(const float* __restrict__ boxes,
                        const int*   __restrict__ labels,
                        const float* __restrict__ priors,
                        ull*      __restrict__ bestpart,
                        unsigned* __restrict__ labobj,
                        int*      __restrict__ chunkdone)
{
    const int b = blockIdx.x / CHUNKS;
    const int chunk = blockIdx.x % CHUNKS;
    const int tid = threadIdx.x;
    const int p = chunk * 256 + tid;
    const bool valid = p < NP;

    __shared__ float bxs[NM][4];
    __shared__ float areaA[NM];
    __shared__ int   labL[NM];
    __shared__ float iouT[256 * 21];   // stride 21: conflict-free transpose
    __shared__ ull   wcand[4][NM];
    __shared__ int   flagLast;
    __shared__ int   pps[NM];

    if (tid < NM * 4) ((float*)bxs)[tid] = boxes[b * NM * 4 + tid];
    if (tid >= 128 && tid < 128 + NM) labL[tid - 128] = labels[b * NM + (tid - 128)];
    if (tid == 0) flagLast = 0;
    __syncthreads();
    if (tid < NM) areaA[tid] = (bxs[tid][2] - bxs[tid][0]) * (bxs[tid][3] - bxs[tid][1]);
    __syncthreads();

    float4 pc = reinterpret_cast<const float4*>(priors)[valid ? p : 0];
    const float px1 = pc.x - pc.z * 0.5f;
    const float py1 = pc.y - pc.w * 0.5f;
    const float px2 = pc.x + pc.z * 0.5f;
    const float py2 = pc.y + pc.w * 0.5f;
    const float pa  = (px2 - px1) * (py2 - py1);

    float bov = -1.f; int bm = 0;
    const int tbase = tid * 21;
#pragma unroll
    for (int m = 0; m < NM; m++) {
        float ix1 = fmaxf(bxs[m][0], px1);
        float iy1 = fmaxf(bxs[m][1], py1);
        float ix2 = fminf(bxs[m][2], px2);
        float iy2 = fminf(bxs[m][3], py2);
        float iw = fmaxf(ix2 - ix1, 0.f);
        float ih = fmaxf(iy2 - iy1, 0.f);
        float inter = iw * ih;
        float iou = inter / (areaA[m] + pa - inter);
        if (iou > bov) { bov = iou; bm = m; }          // first-max over m
        iouT[tbase + m] = valid ? iou : -1.f;
    }
    if (valid) {
        int lab = (bov < 0.5f) ? 0 : labL[bm];
        __hip_atomic_store(&labobj[(size_t)b * NP + p],
                           (unsigned)lab | ((unsigned)bm << 8),
                           __ATOMIC_RELAXED, AGENT);
    }
    __syncthreads();

    // per-object argmax over this chunk's 256 priors: wave w scans its 64 rows
    const int lane = tid & 63, wid = tid >> 6;
    if (lane < NM) {
        const int m = lane;
        float bv = -1.f; int bt = 0;
        const int t0 = wid * 64;
        for (int t = t0; t < t0 + 64; t++) {
            float v = iouT[t * 21 + m];
            if (v > bv) { bv = v; bt = t; }            // strict > keeps min index
        }
        wcand[wid][m] = (bv < 0.f) ? 0ull
            : ((((ull)__float_as_uint(bv)) << 32) | (unsigned)~(unsigned)(chunk * 256 + bt));
    }
    __syncthreads();
    if (tid < NM) {
        ull k = wcand[0][tid];
        if (wcand[1][tid] > k) k = wcand[1][tid];
        if (wcand[2][tid] > k) k = wcand[2][tid];
        if (wcand[3][tid] > k) k = wcand[3][tid];
        __hip_atomic_store(&bestpart[(size_t)(b * CHUNKS + chunk) * NM + tid], k,
                           __ATOMIC_RELAXED, AGENT);
    }
    __syncthreads();
    if (tid == 0) {
        int old = __hip_atomic_fetch_add(&chunkdone[b], 1, __ATOMIC_ACQ_REL, AGENT);
        if (old == CHUNKS - 1) flagLast = 1;
    }
    __syncthreads();

    if (flagLast) {                                    // force-assign (one block/image)
        if (tid < NM) {
            ull k = 0ull;
            for (int c = 0; c < CHUNKS; c++) {
                ull v = __hip_atomic_load(&bestpart[(size_t)(b * CHUNKS + c) * NM + tid],
                                          __ATOMIC_RELAXED, AGENT);
                if (v > k) k = v;
            }
            pps[tid] = (int)~(unsigned)(k & 0xFFFFFFFFull);
        }
        __syncthreads();
        if (tid < NM) {
            int pp = pps[tid];
            bool win = true;
            for (int m2 = tid + 1; m2 < NM; m2++)
                if (pps[m2] == pp) win = false;        // last-write-wins
            if (win)
                __hip_atomic_store(&labobj[(size_t)b * NP + pp],
                                   (unsigned)labL[tid] | ((unsigned)tid << 8),
                                   __ATOMIC_RELAXED, AGENT);
        }
    }
}

// ---------------- K2: CE + loc loss; quad per 4-row group, float4 coalesced ----------------
__global__ __launch_bounds__(256)
void ce_kernel(const float* __restrict__ scores,
               const float* __restrict__ plocs,
               const float* __restrict__ boxes,
               const float* __restrict__ priors,
               const unsigned* __restrict__ labobj,
               float* __restrict__ neg,
               float* __restrict__ perimgPos,
               float* __restrict__ perimgLoc,
               int*   __restrict__ nposarr)
{
    __shared__ float bsum, blocsum;
    __shared__ int   bnp[2];
    const int tid = threadIdx.x;
    if (tid == 0) { bsum = 0.f; blocsum = 0.f; }
    if (tid < 2) bnp[tid] = 0;
    __syncthreads();

    const int q = tid & 3;
    const long long g = (long long)blockIdx.x * 64 + (tid >> 2);
    const bool gvalid = g < NGROUPS;
    // group of 4 rows = 324 floats = exactly 81 float4, 16B-aligned
    const float4* gp = reinterpret_cast<const float4*>(scores) + (gvalid ? g : 0) * 81;

    float s0 = 0.f, s1 = 0.f, s2 = 0.f, s3 = 0.f;
#pragma unroll
    for (int j = 0; j < 20; j++) {
        float4 A = gp[q + 4 * j];
        float ex = __expf(A.x), ey = __expf(A.y), ez = __expf(A.z), ew = __expf(A.w);
        if (j <= 4) {
            s0 += (ex + ey) + (ez + ew);
        } else if (j >= 6 && j <= 9) {
            s1 += (ex + ey) + (ez + ew);
        } else if (j >= 11 && j <= 14) {
            s2 += (ex + ey) + (ez + ew);
        } else if (j >= 16) {
            s3 += (ex + ey) + (ez + ew);
        } else {
            // boundary loads: j==5 (81), j==10 (162), j==15 (243); 2-way split
            const int bnd = (j == 5) ? 81 : (j == 10) ? 162 : 243;
            const int e0 = (q + 4 * j) * 4;
            float lo_ = ((e0     < bnd) ? ex : 0.f) + ((e0 + 1 < bnd) ? ey : 0.f)
                      + ((e0 + 2 < bnd) ? ez : 0.f) + ((e0 + 3 < bnd) ? ew : 0.f);
            float hi_ = ((e0     < bnd) ? 0.f : ex) + ((e0 + 1 < bnd) ? 0.f : ey)
                      + ((e0 + 2 < bnd) ? 0.f : ez) + ((e0 + 3 < bnd) ? 0.f : ew);
            if (j == 5)      { s0 += lo_; s1 += hi_; }
            else if (j == 10){ s1 += lo_; s2 += hi_; }
            else             { s2 += lo_; s3 += hi_; }
        }
    }
    if (q == 0) {                      // float4 idx 80 = elements 320..323, all row 3
        float4 L = gp[80];
        s3 += (__expf(L.x) + __expf(L.y)) + (__expf(L.z) + __expf(L.w));
    }

    // quad-local reduction (DPP-cheap)
    s0 += __shfl_xor(s0, 1);  s0 += __shfl_xor(s0, 2);
    s1 += __shfl_xor(s1, 1);  s1 += __shfl_xor(s1, 2);
    s2 += __shfl_xor(s2, 1);  s2 += __shfl_xor(s2, 2);
    s3 += __shfl_xor(s3, 1);  s3 += __shfl_xor(s3, 2);

    if (gvalid) {
        const float srow = (q == 0) ? s0 : (q == 1) ? s1 : (q == 2) ? s2 : s3;
        const long long r = g * 4 + q;             // this lane's row
        const int b = (int)(r / NP);
        const int p = (int)(r - (long long)b * NP);
        const int bfirst = (int)(((long long)blockIdx.x * 256) / NP);
        const unsigned lo = labobj[r];
        const int lab = lo & 0xFF;
        const int obj = lo >> 8;
        float labval = scores[(size_t)r * NC + lab];   // L1/L2 hit: lines just fetched
        float ce = logf(srow) - labval;                // no-max LSE: |x|<~6, safe

        if (lab > 0) {
            neg[r] = 0.f;
            atomicAdd(&bsum, ce);
            atomicAdd(&bnp[b - bfirst], 1);
            float4 pcr = reinterpret_cast<const float4*>(priors)[p];
            const float* bx = boxes + ((size_t)b * NM + obj) * 4;
            float x1 = bx[0], y1 = bx[1], x2 = bx[2], y2 = bx[3];
            float bcx = (x1 + x2) * 0.5f, bcy = (y1 + y2) * 0.5f;
            float bw = x2 - x1, bh = y2 - y1;
            float g0 = (bcx - pcr.x) / (pcr.z / 10.f);
            float g1 = (bcy - pcr.y) / (pcr.w / 10.f);
            float g2 = logf(bw / pcr.z) * 5.f;
            float g3 = logf(bh / pcr.w) * 5.f;
            float4 pl = reinterpret_cast<const float4*>(plocs)[r];
            float t = 0.f, d, ad;
            d = pl.x - g0; ad = fabsf(d); t += (ad < 1.f) ? 0.5f * d * d : ad - 0.5f;
            d = pl.y - g1; ad = fabsf(d); t += (ad < 1.f) ? 0.5f * d * d : ad - 0.5f;
            d = pl.z - g2; ad = fabsf(d); t += (ad < 1.f) ? 0.5f * d * d : ad - 0.5f;
            d = pl.w - g3; ad = fabsf(d); t += (ad < 1.f) ? 0.5f * d * d : ad - 0.5f;
            atomicAdd(&blocsum, t);
        } else {
            neg[r] = ce;
        }
    }
    __syncthreads();
    if (tid == 0) {
        const int bfirst = (int)(((long long)blockIdx.x * 256) / NP);
        if (bsum != 0.f)    atomicAdd(&perimgPos[bfirst], bsum);
        if (blocsum != 0.f) atomicAdd(&perimgLoc[bfirst], blocsum);
        if (bnp[0] > 0)     atomicAdd(&nposarr[bfirst], bnp[0]);
        if (bnp[1] > 0 && bfirst + 1 < NB) atomicAdd(&nposarr[bfirst + 1], bnp[1]);
    }
}

// ---------------- K3: hard-negative mining + fold + finalize ----------------
__global__ __launch_bounds__(1024)
void mine_kernel(const float* __restrict__ neg,
                 const int*   __restrict__ nposarr,
                 const float* __restrict__ perimgPos,
                 const float* __restrict__ perimgLoc,
                 float* __restrict__ acc,
                 float* __restrict__ out)
{
    __shared__ float vals[NP];
    __shared__ ull   redU[2][16];
    __shared__ float redF[16];
    __shared__ int   redI[16];
    const int b = blockIdx.x;
    const int tid = threadIdx.x;
    const float* src = neg + (size_t)b * NP;
    for (int p = tid; p < NP; p += 1024) vals[p] = src[p];
    int k = nposarr[b] * 3;
    if (k > NP) k = NP;
    __syncthreads();
    const int lane = tid & 63, wid = tid >> 6;

    float t = 0.f;
    if (k > 0) {
        unsigned lo = 0u, hi = 0x7f7fffffu;
        int par = 0;
        while (lo < hi) {
            unsigned u1, u2, u3;
            if (hi - lo >= 3u) {
                unsigned w4 = (hi - lo + 1u) >> 2;
                u1 = lo + w4; u2 = lo + 2u * w4; u3 = lo + 3u * w4;
            } else {
                u1 = u2 = u3 = lo + ((hi - lo + 1u) >> 1);
            }
            float t1 = __uint_as_float(u1), t2 = __uint_as_float(u2), t3 = __uint_as_float(u3);
            ull c = 0ull;
            for (int p = tid; p < NP; p += 1024) {
                float v = vals[p];
                c += (v >= t1 ? 1ull : 0ull)
                   + (v >= t2 ? (1ull << 21) : 0ull)
                   + (v >= t3 ? (1ull << 42) : 0ull);
            }
#pragma unroll
            for (int off = 32; off; off >>= 1) c += __shfl_xor(c, off);
            if (lane == 0) redU[par][wid] = c;
            __syncthreads();
            ull tot = 0ull;
#pragma unroll
            for (int w = 0; w < 16; w++) tot += redU[par][w];
            par ^= 1;                       // double-buffered: 1 barrier/iter
            int c1 = (int)(tot & 0x1FFFFFull);
            int c2 = (int)((tot >> 21) & 0x1FFFFFull);
            int c3 = (int)(tot >> 42);
            if      (c3 >= k) lo = u3;
            else if (c2 >= k) { lo = u2; hi = u3 - 1u; }
            else if (c1 >= k) { lo = u1; hi = u2 - 1u; }
            else              hi = u1 - 1u;
        }
        t = __uint_as_float(lo);            // exact k-th largest
    }
    float s = 0.f; int cg = 0;
    for (int p = tid; p < NP; p += 1024) {
        float v = vals[p];
        if (v > t) { s += v; cg++; }
    }
#pragma unroll
    for (int off = 32; off; off >>= 1) { s += __shfl_down(s, off); cg += __shfl_down(cg, off); }
    if (lane == 0) { redF[wid] = s; redI[wid] = cg; }
    __syncthreads();
    if (tid == 0) {
        float sum = 0.f; int cG = 0;
#pragma unroll
        for (int w = 0; w < 16; w++) { sum += redF[w]; cG += redI[w]; }
        float contrib = (k > 0) ? (sum + (float)(k - cG) * t) : 0.f;
        atomicAdd(&acc[2], contrib);
        atomicAdd(&acc[1], perimgPos[b]);
        atomicAdd(&acc[0], perimgLoc[b]);
        __threadfence();
        int old = atomicAdd((int*)acc + 3, 1);
        if (old == NB - 1) {                // last block: finalize
            __threadfence();
            float nt = 0.f;
            for (int i = 0; i < NB; i++) nt += (float)nposarr[i];
            out[0] = (acc[2] + acc[1]) / nt;   // conf_loss
            out[1] = acc[0] / (nt * 4.f);      // loc_loss (ALPHA=1)
        }
    }
}

extern "C" void kernel_launch(void* const* d_in, const int* in_sizes, int n_in,
                              void* d_out, int out_size, void* d_ws, size_t ws_size,
                              hipStream_t stream)
{
    const float* plocs  = (const float*)d_in[0];
    const float* scores = (const float*)d_in[1];
    const float* boxes  = (const float*)d_in[2];
    const int*   labels = (const int*)d_in[3];
    const float* priors = (const float*)d_in[4];
    float* out = (float*)d_out;

    char* base = (char*)d_ws;
    float*    acc       = (float*)base;
    int*      nposarr   = (int*)(base + 64);
    int*      chunkdone = (int*)(base + 192);
    float*    perimgPos = (float*)(base + 320);
    float*    perimgLoc = (float*)(base + 448);
    ull*      bestpart  = (ull*)(base + 4096);
    unsigned* labobj    = (unsigned*)(base + 196608);
    float*    neg       = (float*)(base + 1314304);

    hipMemsetAsync(d_ws, 0, 4096, stream);
    hipLaunchKernelGGL(match_force_kernel, dim3(NB * CHUNKS), dim3(256), 0, stream,
                       boxes, labels, priors, bestpart, labobj, chunkdone);
    hipLaunchKernelGGL(ce_kernel, dim3(CE_BLOCKS), dim3(256), 0, stream,
                       scores, plocs, boxes, priors, labobj, neg,
                       perimgPos, perimgLoc, nposarr);
    hipLaunchKernelGGL(mine_kernel, dim3(NB), dim3(1024), 0, stream,
                       neg, nposarr, perimgPos, perimgLoc, acc, out);
}